// Round 1
// 165.160 us; speedup vs baseline: 1.0079x; 1.0079x over previous
//
#include <hip/hip_runtime.h>
#include <hip/hip_bf16.h>
#include <hip/hip_fp16.h>

typedef _Float16 half2v __attribute__((ext_vector_type(2)));
typedef _Float16 half8v __attribute__((ext_vector_type(8)));
typedef __attribute__((ext_vector_type(4))) float float4v;

// ---- helpers: inputs are fp32; intermediates are f16 (packed-math friendly) ----
__device__ __forceinline__ half2v u2h(unsigned u) { return __builtin_bit_cast(half2v, u); }
__device__ __forceinline__ unsigned h2u(half2v h) { return __builtin_bit_cast(unsigned, h); }
__device__ __forceinline__ unsigned short f2hu(float f) {
    _Float16 h = (_Float16)f; return __builtin_bit_cast(unsigned short, h);
}
__device__ __forceinline__ unsigned packh(float lo, float hi) {
    half2v h; h[0] = (_Float16)lo; h[1] = (_Float16)hi; return h2u(h);
}
// unpack 8 f16 (16B aligned) to 8 floats (fallback path)
__device__ __forceinline__ void ld8h(const unsigned short* p, float* f) {
    uint4 u = *(const uint4*)p;
    half2v h0 = u2h(u.x), h1 = u2h(u.y), h2 = u2h(u.z), h3 = u2h(u.w);
    f[0] = (float)h0[0]; f[1] = (float)h0[1]; f[2] = (float)h1[0]; f[3] = (float)h1[1];
    f[4] = (float)h2[0]; f[5] = (float)h2[1]; f[6] = (float)h3[0]; f[7] = (float)h3[1];
}

// -------------------------------------------------------------------------
// Kernel 1: fused MFMA 1x1 conv from fp32. Both img tile and W tile staged
// into LDS with inline fp32->f16 conversion (once per block).
// buf[px][1024](f16) = img^T[px][256k] @ (Wk|Wv)^T
// -------------------------------------------------------------------------
__global__ __launch_bounds__(256) void conv_fused_kernel(
    const float* __restrict__ img, const float* __restrict__ Wk,
    const float* __restrict__ Wv, unsigned short* __restrict__ buf)
{
    __shared__ __attribute__((aligned(16))) unsigned short Bt[64][264]; // img [px][k]
    __shared__ __attribute__((aligned(16))) unsigned short Wt[64][264]; // W   [row][k]
    const int tid = threadIdx.x;
    const int p0 = blockIdx.x * 64;
    const int o0 = blockIdx.y * 64;
    const float* Wsel = (o0 < 512) ? Wk : Wv;
    const int obase = (o0 < 512) ? o0 : (o0 - 512);

    // ---- stage img tile transposed (fp32 -> f16) ----
#pragma unroll
    for (int i = 0; i < 4; i++) {
        int chunk = i * 256 + tid;
        int kp  = chunk >> 3;              // k-pair index
        int pxg = (chunk & 7) * 8;         // 8-pixel group
        const float* r0 = img + (size_t)(2 * kp) * 4096 + p0 + pxg;
        const float* r1 = img + (size_t)(2 * kp + 1) * 4096 + p0 + pxg;
        float4 a0 = *(const float4*)r0, a1 = *(const float4*)(r0 + 4);
        float4 b0 = *(const float4*)r1, b1 = *(const float4*)(r1 + 4);
        unsigned lo[8], hi[8];
        lo[0] = f2hu(a0.x); lo[1] = f2hu(a0.y); lo[2] = f2hu(a0.z); lo[3] = f2hu(a0.w);
        lo[4] = f2hu(a1.x); lo[5] = f2hu(a1.y); lo[6] = f2hu(a1.z); lo[7] = f2hu(a1.w);
        hi[0] = f2hu(b0.x); hi[1] = f2hu(b0.y); hi[2] = f2hu(b0.z); hi[3] = f2hu(b0.w);
        hi[4] = f2hu(b1.x); hi[5] = f2hu(b1.y); hi[6] = f2hu(b1.z); hi[7] = f2hu(b1.w);
#pragma unroll
        for (int j = 0; j < 8; j++)
            *(unsigned*)&Bt[pxg + j][2 * kp] = lo[j] | (hi[j] << 16);
    }
    // ---- stage W tile (fp32 -> f16): row = tid>>2, 64 k per quarter ----
    {
        const int row = tid >> 2, q = tid & 3;
        const float* wp = Wsel + (size_t)(obase + row) * 256 + q * 64;
#pragma unroll
        for (int j = 0; j < 8; j++) {
            float4 w0 = *(const float4*)(wp + j * 8);
            float4 w1 = *(const float4*)(wp + j * 8 + 4);
            uint4 pk;
            pk.x = packh(w0.x, w0.y); pk.y = packh(w0.z, w0.w);
            pk.z = packh(w1.x, w1.y); pk.w = packh(w1.z, w1.w);
            *(uint4*)&Wt[row][q * 64 + j * 8] = pk;
        }
    }
    __syncthreads();

    const int w = tid >> 6, l = tid & 63;
    const int m = l & 15, quad = l >> 4;
    const int mrow = w * 16 + m;

    float4v acc[4] = {{0,0,0,0},{0,0,0,0},{0,0,0,0},{0,0,0,0}};
#pragma unroll
    for (int kk = 0; kk < 8; kk++) {
        const int kofs = kk * 32 + quad * 8;
        half8v af = *(const half8v*)&Bt[mrow][kofs];
#pragma unroll
        for (int nt = 0; nt < 4; nt++) {
            half8v b8 = *(const half8v*)&Wt[nt * 16 + m][kofs];
            acc[nt] = __builtin_amdgcn_mfma_f32_16x16x32_f16(af, b8, acc[nt], 0, 0, 0);
        }
    }
#pragma unroll
    for (int nt = 0; nt < 4; nt++) {
#pragma unroll
        for (int r = 0; r < 4; r++) {
            size_t px = p0 + w * 16 + quad * 4 + r;
            buf[px * 1024 + o0 + nt * 16 + m] = f2hu(acc[nt][r]);
        }
    }
}

// -------------------------------------------------------------------------
// Kernel 2: qfull[24576,512](f16) = features[24576,32](fp32) @ Wq[32,512](fp32)
// -------------------------------------------------------------------------
__global__ __launch_bounds__(256) void qgemm_kernel(
    const float* __restrict__ features, const float* __restrict__ Wq,
    unsigned short* __restrict__ qfull)
{
    __shared__ __attribute__((aligned(16))) unsigned short WqT[256][40]; // [n][k]
    const int tid = threadIdx.x;
    const int R0 = blockIdx.x * 64;
    const int n0 = blockIdx.y * 256;
#pragma unroll
    for (int k = 0; k < 32; k++)
        WqT[tid][k] = f2hu(Wq[(size_t)k * 512 + n0 + tid]);
    __syncthreads();

    const int w = tid >> 6, l = tid & 63, m = l & 15, quad = l >> 4;
    const int row = R0 + w * 16 + m;
    const float* fp = features + (size_t)row * 32 + quad * 8;
    float4 f0 = *(const float4*)fp, f1 = *(const float4*)(fp + 4);
    half8v af;
    af[0] = (_Float16)f0.x; af[1] = (_Float16)f0.y;
    af[2] = (_Float16)f0.z; af[3] = (_Float16)f0.w;
    af[4] = (_Float16)f1.x; af[5] = (_Float16)f1.y;
    af[6] = (_Float16)f1.z; af[7] = (_Float16)f1.w;
    float4v acc[16];
#pragma unroll
    for (int t = 0; t < 16; t++) acc[t] = (float4v){0.f, 0.f, 0.f, 0.f};
#pragma unroll
    for (int t = 0; t < 16; t++) {
        half8v b8 = *(const half8v*)&WqT[t * 16 + m][quad * 8];
        acc[t] = __builtin_amdgcn_mfma_f32_16x16x32_f16(af, b8, acc[t], 0, 0, 0);
    }
    const int rb = R0 + w * 16 + quad * 4;
#pragma unroll
    for (int t = 0; t < 16; t++)
#pragma unroll
        for (int r = 0; r < 4; r++)
            qfull[(size_t)(rb + r) * 512 + n0 + t * 16 + m] = f2hu(acc[t][r]);
}

// -------------------------------------------------------------------------
// Kernel 3: per-gaussian sampling + attention core. 1 block = 1 gaussian.
// launch_bounds(256,6): ~80 VGPR cap so stage-5's 8 corner loads stay in flight.
// This revision cuts redundant VALU work:
//  - stage 4 finalizes bilinear addressing per POINT (pix as 4xu16, wt as 4xf16,
//    one 16B LDS record); stage 5 no longer re-derives it 8x per point.
//  - stage 7 emits packed {f16,f16} attention pairs; stage 8 inner loop is pure
//    ds_read + v_pk_fma_f16 (no per-thread cvt/pack of attn weights).
// -------------------------------------------------------------------------
__global__ __launch_bounds__(256, 6) void attn_core_kernel(
    const float* __restrict__ means, const float* __restrict__ scales,
    const float* __restrict__ rot,   const float* __restrict__ transforms,
    const float* __restrict__ projection, const float* __restrict__ W_off,
    const float* __restrict__ b_off, const unsigned short* __restrict__ buf,
    unsigned short* __restrict__ qfull)
{
    __shared__ __attribute__((aligned(16))) unsigned qf2[768];   // q f16-pairs [t][256]
    __shared__ __attribute__((aligned(16))) unsigned vsh2[3072]; // W_off stage | v pairs [p][32]
    __shared__ __attribute__((aligned(16))) float qm_u[512];     // qm (st2-3) | pix_wt[96] uint4 (st4+)
    __shared__ __attribute__((aligned(16))) unsigned att2[288];  // lrn[144]f (st3-4) | att f32 (st5-7) | packed pairs (st7+)
    __shared__ float mw[3], sc3[3], Rt[9], pr[12];

    float* lrn  = (float*)att2;           // 144 floats, live stages 3-4
    float* wofl = (float*)vsh2;           // 1206 floats (live stages 0-3)
    float* bofl = wofl + 1206;            // 18 floats

    const int g = blockIdx.x, tid = threadIdx.x;

    // ---- stage 0: geometry + weight staging + q staging (packed) ----
    for (int i = tid; i < 1206; i += 256) wofl[i] = W_off[i];
    if (tid < 18) bofl[tid] = b_off[tid];
    if (tid >= 32 && tid < 35) {
        sc3[tid - 32] = scales[(size_t)g * 3 + (tid - 32)];
    } else if (tid >= 36 && tid < 48) {
        pr[tid - 36] = projection[tid - 36];
    } else if (tid == 48) {
        float w = rot[(size_t)g * 4],     x = rot[(size_t)g * 4 + 1];
        float y = rot[(size_t)g * 4 + 2], z = rot[(size_t)g * 4 + 3];
        float n = rsqrtf(w * w + x * x + y * y + z * z);
        w *= n; x *= n; y *= n; z *= n;
        float R00 = 1 - 2 * (y * y + z * z), R01 = 2 * (x * y - w * z), R02 = 2 * (x * z + w * y);
        float R10 = 2 * (x * y + w * z), R11 = 1 - 2 * (x * x + z * z), R12 = 2 * (y * z - w * x);
        float R20 = 2 * (x * z - w * y), R21 = 2 * (y * z + w * x), R22 = 1 - 2 * (x * x + y * y);
        Rt[0] = R00; Rt[1] = R10; Rt[2] = R20;
        Rt[3] = R01; Rt[4] = R11; Rt[5] = R21;
        Rt[6] = R02; Rt[7] = R12; Rt[8] = R22;
    } else if (tid >= 52 && tid < 55) {
        int i = tid - 52;
        float m0 = means[(size_t)g * 3];
        float m1 = means[(size_t)g * 3 + 1];
        float m2 = means[(size_t)g * 3 + 2];
        const float* T = transforms + (size_t)g * 16 + i * 4;
        mw[i] = T[0] * m0 + T[1] * m1 + T[2] * m2 + T[3];
    }
    {
        const unsigned* qsrc = (const unsigned*)(qfull + (size_t)g * 1536);
#pragma unroll
        for (int i = 0; i < 3; i++) {
            int e = tid + i * 256;
            qf2[e] = qsrc[e];
        }
    }
    __syncthreads();

    // ---- stage 2: q_mean (one pair per thread) ----
    {
        half2v a = u2h(qf2[tid]), b = u2h(qf2[256 + tid]), c = u2h(qf2[512 + tid]);
        qm_u[tid * 2]     = ((float)a[0] + (float)b[0] + (float)c[0]) * (1.f / 3.f);
        qm_u[tid * 2 + 1] = ((float)a[1] + (float)b[1] + (float)c[1]) * (1.f / 3.f);
    }
    __syncthreads();

    // ---- stage 3: OffsetNet (weights from LDS) ----
    if (tid < 144) {
        int h = tid / 18, l = tid % 18;
        float s = bofl[l];
#pragma unroll
        for (int i = 0; i < 3; i++) s += mw[i] * wofl[i * 18 + l];
        for (int d = 0; d < 64; d++) s += qm_u[h * 64 + d] * wofl[(3 + d) * 18 + l];
        s = fminf(fmaxf(s, -9.21f), 9.21f);
        lrn[tid] = 1.f / (1.f + expf(-s)) - 0.5f;
    }
    __syncthreads();

    // ---- stage 4: per-point bilinear finalize ->
    //      pix_wt[p] = {pix0|pix1<<16, pix2|pix3<<16, packh(w0,w1), packh(w2,w3)}
    if (tid < 96) {
        int h = tid / 12, k = tid % 12;
        float s0, s1, s2;
        if (k < 6) {
            const float FSx[6] = {0.f, 1.f, 0.f, 0.f, -1.f, 0.f};
            const float FSy[6] = {0.f, 0.f, 1.f, 0.f, 0.f, -1.f};
            const float FSz[6] = {0.f, 0.f, 0.f, 1.f, 0.f, 0.f};
            s0 = FSx[k]; s1 = FSy[k]; s2 = FSz[k];
        } else {
            int b = h * 18 + (k - 6) * 3;
            s0 = lrn[b]; s1 = lrn[b + 1]; s2 = lrn[b + 2];
        }
        float o0 = s0 * sc3[0], o1 = s1 * sc3[1], o2 = s2 * sc3[2];
        float wx = Rt[0] * o0 + Rt[1] * o1 + Rt[2] * o2 + mw[0];
        float wy = Rt[3] * o0 + Rt[4] * o1 + Rt[5] * o2 + mw[1];
        float wz = Rt[6] * o0 + Rt[7] * o1 + Rt[8] * o2 + mw[2];
        float px = pr[0] * wx + pr[1] * wy + pr[2]  * wz + pr[3];
        float py = pr[4] * wx + pr[5] * wy + pr[6]  * wz + pr[7];
        float pz = pr[8] * wx + pr[9] * wy + pr[10] * wz + pr[11];
        pz = fmaxf(pz, 1e-5f);
        float gx = fminf(fmaxf(px / pz * (1.f / 64.f), 0.f), 0.9999f);
        float gy = fminf(fmaxf(py / pz * (1.f / 64.f), 0.f), 0.9999f);
        float x = gx * 64.f - 0.5f, y = gy * 64.f - 0.5f;
        float fx = floorf(x), fy = floorf(y);
        int x0 = (int)fx, y0 = (int)fy;
        float wx1 = x - fx, wy1 = y - fy;
        float wx0 = 1.f - wx1, wy0 = 1.f - wy1;
        int xs[2] = {x0, x0 + 1}, ys[2] = {y0, y0 + 1};
        float wxs[2] = {wx0, wx1}, wys[2] = {wy0, wy1};
        unsigned pix[4]; float wf[4];
#pragma unroll
        for (int c = 0; c < 4; c++) {
            int xi = xs[c & 1], yi = ys[c >> 1];
            bool v = ((unsigned)xi < 64u) & ((unsigned)yi < 64u);
            int xc = min(max(xi, 0), 63), yc = min(max(yi, 0), 63);
            pix[c] = (unsigned)(yc * 64 + xc);
            wf[c] = v ? wxs[c & 1] * wys[c >> 1] : 0.f;
        }
        uint4 pw;
        pw.x = pix[0] | (pix[1] << 16);
        pw.y = pix[2] | (pix[3] << 16);
        pw.z = packh(wf[0], wf[1]);
        pw.w = packh(wf[2], wf[3]);
        ((uint4*)qm_u)[tid] = pw;
    }
    __syncthreads();

    // ---- stage 5: batched 8-load gather + packed-f16 bilinear + fdot2 scores ----
    {
        const int slice = tid & 7, grp = tid >> 3;
#pragma unroll
        for (int it = 0; it < 3; it++) {
            const int p = it * 32 + grp;
            const int h = p / 12, k = p - h * 12;
            const uint4 pw = ((const uint4*)qm_u)[p];          // LDS broadcast over 8 slices
            const int off0 = (int)(pw.x & 0xffffu) << 10;
            const int off1 = (int)(pw.x >> 16) << 10;
            const int off2 = (int)(pw.y & 0xffffu) << 10;
            const int off3 = (int)(pw.y >> 16) << 10;
            const half2v w01 = u2h(pw.z), w23 = u2h(pw.w);
            const unsigned short* bp = buf + h * 64 + slice * 8;
            // issue ALL 8 loads before any math (needs the 6-waves VGPR budget)
            uint4 uk[4], uv[4];
            uk[0] = *(const uint4*)(bp + off0); uv[0] = *(const uint4*)(bp + off0 + 512);
            uk[1] = *(const uint4*)(bp + off1); uv[1] = *(const uint4*)(bp + off1 + 512);
            uk[2] = *(const uint4*)(bp + off2); uv[2] = *(const uint4*)(bp + off2 + 512);
            uk[3] = *(const uint4*)(bp + off3); uv[3] = *(const uint4*)(bp + off3 + 512);
            half2v ka2[4] = {{0,0},{0,0},{0,0},{0,0}};
            half2v va2[4] = {{0,0},{0,0},{0,0},{0,0}};
            half2v w2;
            w2[0] = w01[0]; w2[1] = w01[0];
            ka2[0] += w2 * u2h(uk[0].x); ka2[1] += w2 * u2h(uk[0].y);
            ka2[2] += w2 * u2h(uk[0].z); ka2[3] += w2 * u2h(uk[0].w);
            va2[0] += w2 * u2h(uv[0].x); va2[1] += w2 * u2h(uv[0].y);
            va2[2] += w2 * u2h(uv[0].z); va2[3] += w2 * u2h(uv[0].w);
            w2[0] = w01[1]; w2[1] = w01[1];
            ka2[0] += w2 * u2h(uk[1].x); ka2[1] += w2 * u2h(uk[1].y);
            ka2[2] += w2 * u2h(uk[1].z); ka2[3] += w2 * u2h(uk[1].w);
            va2[0] += w2 * u2h(uv[1].x); va2[1] += w2 * u2h(uv[1].y);
            va2[2] += w2 * u2h(uv[1].z); va2[3] += w2 * u2h(uv[1].w);
            w2[0] = w23[0]; w2[1] = w23[0];
            ka2[0] += w2 * u2h(uk[2].x); ka2[1] += w2 * u2h(uk[2].y);
            ka2[2] += w2 * u2h(uk[2].z); ka2[3] += w2 * u2h(uk[2].w);
            va2[0] += w2 * u2h(uv[2].x); va2[1] += w2 * u2h(uv[2].y);
            va2[2] += w2 * u2h(uv[2].z); va2[3] += w2 * u2h(uv[2].w);
            w2[0] = w23[1]; w2[1] = w23[1];
            ka2[0] += w2 * u2h(uk[3].x); ka2[1] += w2 * u2h(uk[3].y);
            ka2[2] += w2 * u2h(uk[3].z); ka2[3] += w2 * u2h(uk[3].w);
            va2[0] += w2 * u2h(uv[3].x); va2[1] += w2 * u2h(uv[3].y);
            va2[2] += w2 * u2h(uv[3].z); va2[3] += w2 * u2h(uv[3].w);

            const int pa = h * 32 + slice * 4;         // pair base
            *(uint4*)&vsh2[p * 32 + slice * 4] =
                make_uint4(h2u(va2[0]), h2u(va2[1]), h2u(va2[2]), h2u(va2[3]));
            float sp[3];
#pragma unroll
            for (int t = 0; t < 3; t++) {
                uint4 q4 = *(const uint4*)&qf2[t * 256 + pa];
                float s = __builtin_amdgcn_fdot2(u2h(q4.x), ka2[0], 0.f, false);
                s = __builtin_amdgcn_fdot2(u2h(q4.y), ka2[1], s, false);
                s = __builtin_amdgcn_fdot2(u2h(q4.z), ka2[2], s, false);
                s = __builtin_amdgcn_fdot2(u2h(q4.w), ka2[3], s, false);
                sp[t] = s;
            }
#pragma unroll
            for (int msk = 1; msk < 8; msk <<= 1) {
#pragma unroll
                for (int t = 0; t < 3; t++) sp[t] += __shfl_xor(sp[t], msk);
            }
            if (slice == 0) {
#pragma unroll
                for (int t = 0; t < 3; t++)
                    ((float*)att2)[(h * 3 + t) * 12 + k] = sp[t] * 0.125f;
            }
        }
    }
    __syncthreads();

    // ---- stage 7: softmax over K=12, emit packed {f16,f16} pairs in place ----
    if (tid < 24) {
        float*    row  = (float*)att2 + tid * 12;
        unsigned* rowp = att2 + tid * 12;
        float m = row[0];
#pragma unroll
        for (int k = 1; k < 12; k++) m = fmaxf(m, row[k]);
        float e_[12]; float ssum = 0.f;
#pragma unroll
        for (int k = 0; k < 12; k++) { e_[k] = expf(row[k] - m); ssum += e_[k]; }
        float inv = 1.f / ssum;
#pragma unroll
        for (int k = 0; k < 12; k++) { float a = e_[k] * inv; rowp[k] = packh(a, a); }
    }
    __syncthreads();

    // ---- stage 8: out_attn = attn @ v_s via pk_fma on packed pairs ----
    {
        unsigned* oa32 = (unsigned*)(qfull + (size_t)g * 1536);
#pragma unroll
        for (int i = 0; i < 3; i++) {
            int e = tid + i * 256;            // pair index 0..767
            int t = e >> 8, a2p = e & 255;
            int h = a2p >> 5, ddp = a2p & 31;
            const unsigned* ar2 = att2 + (h * 3 + t) * 12;
            const unsigned* vp  = vsh2 + h * 12 * 32 + ddp;
            half2v acc = {0, 0};
#pragma unroll
            for (int k = 0; k < 12; k++)
                acc += u2h(ar2[k]) * u2h(vp[k * 32]);
            oa32[e] = h2u(acc);
        }
    }
}

// -------------------------------------------------------------------------
// Kernel 4: out[24576,32](fp32) = oa[24576,512](f16) @ Wout[512,32](fp32)
//           + b_out + features
// -------------------------------------------------------------------------
__global__ __launch_bounds__(256) void outgemm_kernel(
    const unsigned short* __restrict__ oa, const float* __restrict__ Wout,
    const float* __restrict__ b_out, const float* __restrict__ features,
    float* __restrict__ out)
{
    __shared__ __attribute__((aligned(16))) unsigned short WT[32][520]; // [n][k]
    const int tid = threadIdx.x;
    const int R0 = blockIdx.x * 64;
#pragma unroll
    for (int j = 0; j < 64; j++) {
        int lin = j * 256 + tid;         // lin = k*32 + n
        WT[lin & 31][lin >> 5] = f2hu(Wout[lin]);
    }
    __syncthreads();

    const int w = tid >> 6, l = tid & 63, m = l & 15, quad = l >> 4;
    const int row = R0 + w * 16 + m;
    float4v acc[2] = {{0,0,0,0},{0,0,0,0}};
#pragma unroll
    for (int kk = 0; kk < 16; kk++) {
        half8v af = *(const half8v*)(oa + (size_t)row * 512 + kk * 32 + quad * 8);
#pragma unroll
        for (int t = 0; t < 2; t++) {
            half8v b8 = *(const half8v*)&WT[t * 16 + m][kk * 32 + quad * 8];
            acc[t] = __builtin_amdgcn_mfma_f32_16x16x32_f16(af, b8, acc[t], 0, 0, 0);
        }
    }
    const int rb = R0 + w * 16 + quad * 4;
#pragma unroll
    for (int t = 0; t < 2; t++) {
        int col = t * 16 + m;
        float bb = b_out[col];
#pragma unroll
        for (int r = 0; r < 4; r++) {
            int rr = rb + r;
            out[(size_t)rr * 32 + col] = acc[t][r] + bb + features[(size_t)rr * 32 + col];
        }
    }
}

// -------------------------------------------------------------------------
// Fallback (ws too small): fused attention kernel, fp32 inputs, f16 buf.
// -------------------------------------------------------------------------
__global__ __launch_bounds__(256, 6) void attn_fused_kernel(
    const float* __restrict__ means, const float* __restrict__ scales,
    const float* __restrict__ rot,   const float* __restrict__ features,
    const float* __restrict__ transforms, const float* __restrict__ projection,
    const float* __restrict__ Wq,    const float* __restrict__ W_off,
    const float* __restrict__ b_off, const float* __restrict__ Wout,
    const float* __restrict__ b_out, const unsigned short* __restrict__ buf,
    float* __restrict__ out)
{
    __shared__ float feat[96];
    __shared__ __attribute__((aligned(16))) float qf[1536];
    __shared__ float qm[512];
    __shared__ float mw[3], sc3[3], Rt[9], pr[12];
    __shared__ float lrn[144];
    __shared__ int   coff[96][4];
    __shared__ float cwt[96][4];
    __shared__ __attribute__((aligned(16))) char pool[12288];
    __shared__ float att[288];

    unsigned short* vsh = (unsigned short*)pool;
    const int g = blockIdx.x, tid = threadIdx.x;

    if (tid < 96) {
        feat[tid] = features[(size_t)g * 96 + tid];
    } else if (tid < 99) {
        sc3[tid - 96] = scales[(size_t)g * 3 + (tid - 96)];
    } else if (tid >= 100 && tid < 112) {
        pr[tid - 100] = projection[tid - 100];
    } else if (tid == 112) {
        float w = rot[(size_t)g * 4],     x = rot[(size_t)g * 4 + 1];
        float y = rot[(size_t)g * 4 + 2], z = rot[(size_t)g * 4 + 3];
        float n = rsqrtf(w * w + x * x + y * y + z * z);
        w *= n; x *= n; y *= n; z *= n;
        float R00 = 1 - 2 * (y * y + z * z), R01 = 2 * (x * y - w * z), R02 = 2 * (x * z + w * y);
        float R10 = 2 * (x * y + w * z), R11 = 1 - 2 * (x * x + z * z), R12 = 2 * (y * z - w * x);
        float R20 = 2 * (x * z - w * y), R21 = 2 * (y * z + w * x), R22 = 1 - 2 * (x * x + y * y);
        Rt[0] = R00; Rt[1] = R10; Rt[2] = R20;
        Rt[3] = R01; Rt[4] = R11; Rt[5] = R21;
        Rt[6] = R02; Rt[7] = R12; Rt[8] = R22;
    } else if (tid >= 116 && tid < 119) {
        int i = tid - 116;
        float m0 = means[(size_t)g * 3];
        float m1 = means[(size_t)g * 3 + 1];
        float m2 = means[(size_t)g * 3 + 2];
        const float* T = transforms + (size_t)g * 16 + i * 4;
        mw[i] = T[0] * m0 + T[1] * m1 + T[2] * m2 + T[3];
    }
    __syncthreads();

    {
        const int a0 = tid * 2;
        float s00 = 0.f, s01 = 0.f, s10 = 0.f, s11 = 0.f, s20 = 0.f, s21 = 0.f;
#pragma unroll
        for (int f = 0; f < 32; f++) {
            float2 w2 = *(const float2*)(Wq + (size_t)f * 512 + a0);
            float f0 = feat[f], f1 = feat[32 + f], f2 = feat[64 + f];
            s00 += f0 * w2.x; s01 += f0 * w2.y;
            s10 += f1 * w2.x; s11 += f1 * w2.y;
            s20 += f2 * w2.x; s21 += f2 * w2.y;
        }
        *(float2*)(qf + a0)        = make_float2(s00, s01);
        *(float2*)(qf + 512 + a0)  = make_float2(s10, s11);
        *(float2*)(qf + 1024 + a0) = make_float2(s20, s21);
    }
    __syncthreads();

    qm[tid]       = (qf[tid]       + qf[tid + 512] + qf[tid + 1024]) * (1.f / 3.f);
    qm[tid + 256] = (qf[tid + 256] + qf[tid + 768] + qf[tid + 1280]) * (1.f / 3.f);
    __syncthreads();

    if (tid < 144) {
        int h = tid / 18, l = tid % 18;
        float s = b_off[l];
#pragma unroll
        for (int i = 0; i < 3; i++) s += mw[i] * W_off[i * 18 + l];
        for (int d = 0; d < 64; d++) s += qm[h * 64 + d] * W_off[(size_t)(3 + d) * 18 + l];
        s = fminf(fmaxf(s, -9.21f), 9.21f);
        lrn[tid] = 1.f / (1.f + expf(-s)) - 0.5f;
    }
    __syncthreads();

    if (tid < 96) {
        int h = tid / 12, k = tid % 12;
        float s0, s1, s2;
        if (k < 6) {
            const float FSx[6] = {0.f, 1.f, 0.f, 0.f, -1.f, 0.f};
            const float FSy[6] = {0.f, 0.f, 1.f, 0.f, 0.f, -1.f};
            const float FSz[6] = {0.f, 0.f, 0.f, 1.f, 0.f, 0.f};
            s0 = FSx[k]; s1 = FSy[k]; s2 = FSz[k];
        } else {
            int b = h * 18 + (k - 6) * 3;
            s0 = lrn[b]; s1 = lrn[b + 1]; s2 = lrn[b + 2];
        }
        float o0 = s0 * sc3[0], o1 = s1 * sc3[1], o2 = s2 * sc3[2];
        float wx = Rt[0] * o0 + Rt[1] * o1 + Rt[2] * o2 + mw[0];
        float wy = Rt[3] * o0 + Rt[4] * o1 + Rt[5] * o2 + mw[1];
        float wz = Rt[6] * o0 + Rt[7] * o1 + Rt[8] * o2 + mw[2];
        float px = pr[0] * wx + pr[1] * wy + pr[2]  * wz + pr[3];
        float py = pr[4] * wx + pr[5] * wy + pr[6]  * wz + pr[7];
        float pz = pr[8] * wx + pr[9] * wy + pr[10] * wz + pr[11];
        pz = fmaxf(pz, 1e-5f);
        float gx = fminf(fmaxf(px / pz * (1.f / 64.f), 0.f), 0.9999f);
        float gy = fminf(fmaxf(py / pz * (1.f / 64.f), 0.f), 0.9999f);
        float x = gx * 64.f - 0.5f, y = gy * 64.f - 0.5f;
        float fx = floorf(x), fy = floorf(y);
        int x0 = (int)fx, y0 = (int)fy;
        float wx1 = x - fx, wx0c = 1.f - wx1;
        float wy1 = y - fy, wy0c = 1.f - wy1;
        int xs[2] = {x0, x0 + 1}, ys[2] = {y0, y0 + 1};
        float wxs[2] = {wx0c, wx1}, wys[2] = {wy0c, wy1};
#pragma unroll
        for (int c = 0; c < 4; c++) {
            int dx = c & 1, dy = c >> 1;
            int xi = xs[dx], yi = ys[dy];
            bool v = (xi >= 0) & (xi < 64) & (yi >= 0) & (yi < 64);
            int xc = min(max(xi, 0), 63), yc = min(max(yi, 0), 63);
            coff[tid][c] = (yc * 64 + xc) * 1024;
            cwt[tid][c]  = v ? wxs[dx] * wys[dy] : 0.f;
        }
    }
    __syncthreads();

    {
        const int slice = tid & 7, d0 = slice * 8, grp = tid >> 3;
#pragma unroll
        for (int it = 0; it < 3; it++) {
            const int p = it * 32 + grp;
            const int h = p / 12, k = p - h * 12;
            const int a = h * 64 + d0;
            const unsigned short* bp = buf + a;
            float ka[8] = {0,0,0,0,0,0,0,0}, va[8] = {0,0,0,0,0,0,0,0}, t8[8];
#pragma unroll
            for (int c = 0; c < 4; c++) {
                const int   o = coff[p][c];
                const float w = cwt[p][c];
                ld8h(bp + o, t8);
#pragma unroll
                for (int j = 0; j < 8; j++) ka[j] += w * t8[j];
                ld8h(bp + o + 512, t8);
#pragma unroll
                for (int j = 0; j < 8; j++) va[j] += w * t8[j];
            }
            uint4 pv;
            pv.x = packh(va[0], va[1]); pv.y = packh(va[2], va[3]);
            pv.z = packh(va[4], va[5]); pv.w = packh(va[6], va[7]);
            *(uint4*)(vsh + p * 64 + d0) = pv;
            float sp[3];
#pragma unroll
            for (int t = 0; t < 3; t++) {
                const float* qp = qf + t * 512 + a;
                float s = 0.f;
#pragma unroll
                for (int j = 0; j < 8; j++) s += qp[j] * ka[j];
                sp[t] = s;
            }
#pragma unroll
            for (int msk = 1; msk < 8; msk <<= 1) {
#pragma unroll
                for (int t = 0; t < 3; t++) sp[t] += __shfl_xor(sp[t], msk);
            }
            if (slice == 0) {
#pragma unroll
                for (int t = 0; t < 3; t++) att[(h * 3 + t) * 12 + k] = sp[t] * 0.125f;
            }
        }
    }
    __syncthreads();

    if (tid < 24) {
        float* row = att + tid * 12;
        float m = row[0];
#pragma unroll
        for (int k = 1; k < 12; k++) m = fmaxf(m, row[k]);
        float e_[12]; float ssum = 0.f;
#pragma unroll
        for (int k = 0; k < 12; k++) { e_[k] = expf(row[k] - m); ssum += e_[k]; }
        float inv = 1.f / ssum;
#pragma unroll
        for (int k = 0; k < 12; k++) row[k] = e_[k] * inv;
    }
    __syncthreads();

#pragma unroll
    for (int i = 0; i < 6; i++) {
        int e = tid + i * 256;
        int t = e >> 9, a = e & 511, h = a >> 6, dd = a & 63;
        const float* ar = att + (h * 3 + t) * 12;
        const unsigned short* vp = vsh + (h * 12) * 64 + dd;
        float s = 0.f;
#pragma unroll
        for (int k = 0; k < 12; k++) {
            _Float16 hh = __builtin_bit_cast(_Float16, vp[k * 64]);
            s += ar[k] * (float)hh;
        }
        qf[e] = s;
    }
    __syncthreads();

    {
        float* red = (float*)pool;
        const int c0 = (tid & 15) * 2, slice = tid >> 4;
        const int abase = slice * 32;
        float a00 = 0.f, a01 = 0.f, a10 = 0.f, a11 = 0.f, a20 = 0.f, a21 = 0.f;
#pragma unroll
        for (int i = 0; i < 32; i++) {
            int a = abase + i;
            float2 w2 = *(const float2*)(Wout + (size_t)a * 32 + c0);
            float o0 = qf[a], o1 = qf[512 + a], o2 = qf[1024 + a];
            a00 += o0 * w2.x; a01 += o0 * w2.y;
            a10 += o1 * w2.x; a11 += o1 * w2.y;
            a20 += o2 * w2.x; a21 += o2 * w2.y;
        }
        __syncthreads();
        red[(slice * 3 + 0) * 32 + c0] = a00; red[(slice * 3 + 0) * 32 + c0 + 1] = a01;
        red[(slice * 3 + 1) * 32 + c0] = a10; red[(slice * 3 + 1) * 32 + c0 + 1] = a11;
        red[(slice * 3 + 2) * 32 + c0] = a20; red[(slice * 3 + 2) * 32 + c0 + 1] = a21;
        __syncthreads();
        if (tid < 96) {
            int t = tid >> 5, c = tid & 31;
            float acc = b_out[c] + feat[tid];
#pragma unroll
            for (int s = 0; s < 16; s++) acc += red[(s * 3 + t) * 32 + c];
            out[(size_t)g * 96 + tid] = acc;
        }
    }
}

extern "C" void kernel_launch(void* const* d_in, const int* in_sizes, int n_in,
                              void* d_out, int out_size, void* d_ws, size_t ws_size,
                              hipStream_t stream) {
    const float* means      = (const float*)d_in[0];
    const float* scales     = (const float*)d_in[1];
    const float* rot        = (const float*)d_in[2];
    const float* features   = (const float*)d_in[3];
    const float* transforms = (const float*)d_in[4];
    const float* projection = (const float*)d_in[5];
    const float* img        = (const float*)d_in[6];
    const float* Wq         = (const float*)d_in[7];
    const float* Wk         = (const float*)d_in[8];
    const float* Wv         = (const float*)d_in[9];
    const float* W_off      = (const float*)d_in[10];
    const float* b_off      = (const float*)d_in[11];
    const float* Wout       = (const float*)d_in[12];
    const float* b_out      = (const float*)d_in[13];
    float* out = (float*)d_out;

    char* w = (char*)d_ws;
    unsigned short* buf = (unsigned short*)(w + 64);   // 4096 x 1024 f16 = 8 MiB
    const size_t BUF_BYTES = (size_t)4096 * 1024 * 2;
    const size_t Q_BYTES   = (size_t)24576 * 512 * 2;  // 24 MiB
    const size_t need = 64 + BUF_BYTES + Q_BYTES;

    dim3 gridc(64, 16);
    conv_fused_kernel<<<gridc, 256, 0, stream>>>(img, Wk, Wv, buf);

    if (ws_size >= need) {
        unsigned short* qfull = (unsigned short*)(w + 64 + BUF_BYTES);
        dim3 gridq(384, 2);
        qgemm_kernel<<<gridq, 256, 0, stream>>>(features, Wq, qfull);
        attn_core_kernel<<<8192, 256, 0, stream>>>(
            means, scales, rot, transforms, projection, W_off, b_off, buf, qfull);
        outgemm_kernel<<<384, 256, 0, stream>>>(qfull, Wout, b_out, features, out);
    } else {
        attn_fused_kernel<<<8192, 256, 0, stream>>>(
            means, scales, rot, features, transforms, projection,
            Wq, W_off, b_off, Wout, b_out, buf, out);
    }
}